// Round 6
// baseline (876.869 us; speedup 1.0000x reference)
//
#include <hip/hip_runtime.h>

#define EPS 1e-6f
#define LN_EPS 1e-5f

typedef unsigned short u16;
typedef unsigned int u32;
typedef short bf16x8 __attribute__((ext_vector_type(8)));
typedef float f32x4 __attribute__((ext_vector_type(4)));

__device__ __forceinline__ float bf2f(u16 u) {
  return __uint_as_float(((u32)u) << 16);
}
__device__ __forceinline__ u16 f2bf(float f) {
  u32 x = __float_as_uint(f);
  x += 0x7fffu + ((x >> 16) & 1u);
  return (u16)(x >> 16);
}

// ------------------------------------------- init slots + zero upd/sums
__global__ void init_slots_kernel(const float* __restrict__ w,
                                  const float* __restrict__ z,
                                  const float* __restrict__ sigma,
                                  float* __restrict__ slots,
                                  float* __restrict__ upd,
                                  float* __restrict__ sums) {
  int i = blockIdx.x * 256 + threadIdx.x;  // < 90112
  int s = i & 255;
  int k = (i >> 8) % 11;
  float wv = w[k * 256 + s];
  slots[i] = wv + z[i] * sigma[0] * wv;
  upd[i] = 0.f;
  if (i < 352) sums[i] = 0.f;
}

// -------------------------------------------------- weight prep (one kernel)
__global__ void wprep_kernel(const float* __restrict__ W_ih,
                             const float* __restrict__ W_hh,
                             const float* __restrict__ W1,
                             const float* __restrict__ W2,
                             const float* __restrict__ Wq,
                             const float* __restrict__ Wk,
                             const float* __restrict__ Wv,
                             float* __restrict__ wihT, float* __restrict__ whhT,
                             short* __restrict__ W1b, short* __restrict__ W2b,
                             short* __restrict__ Wqb, short* __restrict__ Btb) {
  int e = blockIdx.x * 256 + threadIdx.x;
  if (e < 196608) {
    int j = e >> 8, d = e & 255;
    wihT[d * 768 + j] = W_ih[e];
  } else if (e < 393216) {
    int e2 = e - 196608;
    int j = e2 >> 8, d = e2 & 255;
    whhT[d * 768 + j] = W_hh[e2];
  } else if (e < 655360) {
    int e2 = e - 393216;
    W1b[e2] = (short)f2bf(W1[e2]);
  } else if (e < 917504) {
    int e2 = e - 655360;
    W2b[e2] = (short)f2bf(W2[e2]);
  } else if (e < 983040) {
    int e2 = e - 917504;
    Wqb[e2] = (short)f2bf(Wq[e2]);
  } else if (e < 1114112) {
    int e2 = e - 983040;
    int f = e2 >> 9, j = e2 & 511;
    float v = (j < 256) ? Wk[f * 256 + j] : Wv[f * 256 + (j - 256)];
    Btb[j * 256 + f] = (short)f2bf(v);
  }
}

// --------------------------------------------------- MFMA k+v projection
// ktv[j][i] = (LN(features) @ [Wk|Wv])^T, j=0..255 -> k^T (by f), 256..511 ->
// v^T (by s). 64-row blocks (grid 2048); full-K A tile (fused LN -> bf16)
// staged once in 32KB LDS; B fragments loaded DIRECTLY from global (Btb is
// 256KB, L2-resident) -> no Bs, no K-loop barriers, 5 blocks/CU.
// A swizzle (injective + bank-balanced): chunk q of row r at
//   p = (q & 24) | ((q + 2*(q>>3) + r) & 7)
__global__ __launch_bounds__(256) void gemm_kv(
    const float* __restrict__ feat, const short* __restrict__ Btb,
    const float* __restrict__ gf, const float* __restrict__ bfp,
    short* __restrict__ ktv) {
  __shared__ short As[16384];  // 64 rows x 256 k
  int t = threadIdx.x;
  int w = t >> 6, lane = t & 63;
  int quad = lane >> 4, l16 = lane & 15;
  int i0 = blockIdx.x * 64;
  int wi = (w & 1) * 32, wj = (w >> 1) * 64;

  // ---- stage A: fused LN stats + bf16 cvt (thread = quarter of row)
  {
    int r = t >> 2;   // 0..63
    int qd = t & 3;   // quarter
    const float* frow = feat + (long)(i0 + r) * 256 + qd * 64;
    float4 fv[16];
    float s = 0.f, s2 = 0.f;
    #pragma unroll
    for (int i = 0; i < 16; ++i) {
      fv[i] = *(const float4*)(frow + i * 4);
      s += fv[i].x + fv[i].y + fv[i].z + fv[i].w;
      s2 += fv[i].x * fv[i].x + fv[i].y * fv[i].y + fv[i].z * fv[i].z +
            fv[i].w * fv[i].w;
    }
    s += __shfl_xor(s, 1); s2 += __shfl_xor(s2, 1);
    s += __shfl_xor(s, 2); s2 += __shfl_xor(s2, 2);
    float mu = s * (1.f / 256.f);
    float rs = rsqrtf(s2 * (1.f / 256.f) - mu * mu + LN_EPS);
    #pragma unroll
    for (int c = 0; c < 8; ++c) {
      float4 a = fv[c * 2], b = fv[c * 2 + 1];
      int fb = qd * 64 + c * 8;
      float4 g0 = *(const float4*)(gf + fb);
      float4 g1 = *(const float4*)(gf + fb + 4);
      float4 e0 = *(const float4*)(bfp + fb);
      float4 e1 = *(const float4*)(bfp + fb + 4);
      bf16x8 pk;
      pk[0] = (short)f2bf((a.x - mu) * rs * g0.x + e0.x);
      pk[1] = (short)f2bf((a.y - mu) * rs * g0.y + e0.y);
      pk[2] = (short)f2bf((a.z - mu) * rs * g0.z + e0.z);
      pk[3] = (short)f2bf((a.w - mu) * rs * g0.w + e0.w);
      pk[4] = (short)f2bf((b.x - mu) * rs * g1.x + e1.x);
      pk[5] = (short)f2bf((b.y - mu) * rs * g1.y + e1.y);
      pk[6] = (short)f2bf((b.z - mu) * rs * g1.z + e1.z);
      pk[7] = (short)f2bf((b.w - mu) * rs * g1.w + e1.w);
      int p = qd * 8 + ((c + 2 * qd + r) & 7);
      *(bf16x8*)&As[r * 256 + p * 8] = pk;
    }
  }
  __syncthreads();

  const short* bb = Btb + (long)(wj + l16) * 256 + quad * 8;
  for (int jq = 0; jq < 4; ++jq) {
    f32x4 acc[2][4];
    #pragma unroll
    for (int a = 0; a < 2; ++a)
      #pragma unroll
      for (int b = 0; b < 4; ++b) acc[a][b] = (f32x4){0.f, 0.f, 0.f, 0.f};
    #pragma unroll
    for (int ks = 0; ks < 4; ++ks) {
      #pragma unroll
      for (int kh = 0; kh < 2; ++kh) {
        int koff = ks * 64 + kh * 32;
        bf16x8 af[2], bfr[4];
        #pragma unroll
        for (int mi = 0; mi < 2; ++mi) {
          int m = wi + mi * 16 + l16;
          int p = ks * 8 + ((kh * 4 + quad + 2 * ks + m) & 7);
          af[mi] = *(const bf16x8*)&As[m * 256 + p * 8];
        }
        #pragma unroll
        for (int ni = 0; ni < 4; ++ni)
          bfr[ni] = *(const bf16x8*)&bb[(long)(jq * 128 + ni * 16) * 256 + koff];
        #pragma unroll
        for (int mi = 0; mi < 2; ++mi)
          #pragma unroll
          for (int ni = 0; ni < 4; ++ni)
            acc[mi][ni] = __builtin_amdgcn_mfma_f32_16x16x32_bf16(
                af[mi], bfr[ni], acc[mi][ni], 0, 0, 0);
      }
    }
    // D[j,i]: col(l16)=j, row(quad*4+reg)=i -> ktv[j][i] packed in i
    #pragma unroll
    for (int ni = 0; ni < 4; ++ni) {
      int j = jq * 128 + wj + ni * 16 + l16;
      #pragma unroll
      for (int mi = 0; mi < 2; ++mi) {
        long ib = i0 + wi + mi * 16 + quad * 4;
        ushort4 u;
        u.x = f2bf(acc[mi][ni][0]);
        u.y = f2bf(acc[mi][ni][1]);
        u.z = f2bf(acc[mi][ni][2]);
        u.w = f2bf(acc[mi][ni][3]);
        *(ushort4*)&ktv[(long)j * 131072 + ib] = u;
      }
    }
  }
}

// ----------------------------------------------------- q projection (iter 0)
__global__ __launch_bounds__(256) void qproj_kernel(
    const float* __restrict__ slots, const float* __restrict__ gs,
    const float* __restrict__ bs, const short* __restrict__ Wqb,
    float* __restrict__ qout) {
  __shared__ float lnq[256];
  __shared__ float red[8];
  int row = blockIdx.x, t = threadIdx.x;
  int w = t >> 6, lane = t & 63;
  float x = slots[(long)row * 256 + t];
  float s = x, s2 = x * x;
  #pragma unroll
  for (int off = 32; off > 0; off >>= 1) {
    s += __shfl_xor(s, off);
    s2 += __shfl_xor(s2, off);
  }
  if (lane == 0) { red[w * 2] = s; red[w * 2 + 1] = s2; }
  __syncthreads();
  float st = red[0] + red[2] + red[4] + red[6];
  float st2 = red[1] + red[3] + red[5] + red[7];
  float mu = st * (1.f / 256.f);
  float rs = rsqrtf(st2 * (1.f / 256.f) - mu * mu + LN_EPS);
  lnq[t] = (x - mu) * rs * gs[t] + bs[t];
  __syncthreads();
  float acc = 0.f;
  for (int k = 0; k < 256; ++k)
    acc += lnq[k] * bf2f((u16)Wqb[k * 256 + t]);
  qout[(long)row * 256 + t] = acc;
}

// --------------------------------------- fused attention softmax + updates
// Grid (16,32): block = 256 n of one batch. Phase 1: thread = n -> logits via
// coalesced kt[f][i] u16 loads + q broadcasts from LDS, softmax over 11 slots
// in-thread, P -> LDS bf16 [16][264] (+ attn out on last iter, + sums
// atomics). Phase 2 (MFMA): upd^T[s][kk] = sum_n vT[s][n] * P[kk][n];
// A-frag = vT direct from global (16B contig), B-frag = P from LDS.
// Lanes l16<11 atomicAdd into upd (UNNORMALIZED; slot_step divides).
__global__ __launch_bounds__(256) void attn_upd(
    const float* __restrict__ q, const short* __restrict__ ktv,
    float* __restrict__ attn_out, float* __restrict__ sums,
    float* __restrict__ upd, int emit_attn) {
  __shared__ float qs[3072];      // [f][12]
  __shared__ short ps[16 * 264];  // [kk][n] bf16, padded stride 264
  int b = blockIdx.y;
  int n0 = blockIdx.x * 256;
  int t = threadIdx.x, lane = t & 63;
  int w = t >> 6, quad = lane >> 4, l16 = lane & 15;
  for (int e = t; e < 2816; e += 256) {
    int kk = e >> 8, f = e & 255;
    qs[f * 12 + kk] = q[b * 2816 + e];
  }
  for (int e = t; e < 5 * 264; e += 256) ps[11 * 264 + e] = 0;  // pad rows
  __syncthreads();
  long bn = (long)b * 4096 + n0 + t;
  float a[11];
  #pragma unroll
  for (int kk = 0; kk < 11; ++kk) a[kk] = 0.f;
  for (int f = 0; f < 256; ++f) {
    float kv = bf2f((u16)ktv[(long)f * 131072 + bn]);
    float4 qa = *(const float4*)&qs[f * 12];
    float4 qb4 = *(const float4*)&qs[f * 12 + 4];
    float4 qc = *(const float4*)&qs[f * 12 + 8];
    a[0] += kv * qa.x;  a[1] += kv * qa.y;  a[2] += kv * qa.z;
    a[3] += kv * qa.w;  a[4] += kv * qb4.x; a[5] += kv * qb4.y;
    a[6] += kv * qb4.z; a[7] += kv * qb4.w; a[8] += kv * qc.x;
    a[9] += kv * qc.y;  a[10] += kv * qc.z;
  }
  float mx = -1e30f;
  #pragma unroll
  for (int kk = 0; kk < 11; ++kk) {
    a[kk] *= 0.0625f;  // 256^-0.5
    mx = fmaxf(mx, a[kk]);
  }
  float ssum = 0.f;
  #pragma unroll
  for (int kk = 0; kk < 11; ++kk) {
    a[kk] = expf(a[kk] - mx);
    ssum += a[kk];
  }
  float inv = 1.0f / ssum;
  #pragma unroll
  for (int kk = 0; kk < 11; ++kk) {
    float p = a[kk] * inv;
    a[kk] = p;
    ps[kk * 264 + t] = (short)f2bf(p);
    if (emit_attn) attn_out[((long)b * 11 + kk) * 4096 + n0 + t] = p;
  }
  #pragma unroll
  for (int kk = 0; kk < 11; ++kk) {
    float sv = a[kk];
    #pragma unroll
    for (int off = 32; off > 0; off >>= 1) sv += __shfl_xor(sv, off);
    if (lane == 0) atomicAdd(&sums[b * 11 + kk], sv);
  }
  __syncthreads();
  // ---- phase 2: MFMA. wave w -> s-tiles w*4..w*4+3.
  const short* vT = ktv + (long)256 * 131072;
  f32x4 acc[4];
  #pragma unroll
  for (int mi = 0; mi < 4; ++mi) acc[mi] = (f32x4){0.f, 0.f, 0.f, 0.f};
  #pragma unroll
  for (int kst = 0; kst < 8; ++kst) {
    int nb = kst * 32 + quad * 8;
    bf16x8 bps = *(const bf16x8*)&ps[l16 * 264 + nb];
    #pragma unroll
    for (int mi = 0; mi < 4; ++mi) {
      int s = (w * 4 + mi) * 16 + l16;
      bf16x8 av = *(const bf16x8*)&vT[(long)s * 131072 + (long)b * 4096 + n0 + nb];
      acc[mi] = __builtin_amdgcn_mfma_f32_16x16x32_bf16(av, bps, acc[mi], 0, 0, 0);
    }
  }
  // D^T[s][kk]: col(l16)=kk, row(quad*4+reg)=s within tile
  if (l16 < 11) {
    #pragma unroll
    for (int mi = 0; mi < 4; ++mi) {
      int sb = (w * 4 + mi) * 16 + quad * 4;
      #pragma unroll
      for (int r = 0; r < 4; ++r)
        atomicAdd(&upd[((long)b * 11 + l16) * 256 + sb + r], acc[mi][r]);
    }
  }
}

// -------------------------------------------- fused slot step (2 rows/block)
__global__ __launch_bounds__(256) void slot_step(
    float* __restrict__ upd, float* __restrict__ sums,
    const float* __restrict__ slots_in,
    const float* __restrict__ wihT, const float* __restrict__ whhT,
    const float* __restrict__ b_ih, const float* __restrict__ b_hh,
    const float* __restrict__ gm, const float* __restrict__ bm,
    const short* __restrict__ W1b, const float* __restrict__ b1,
    const short* __restrict__ W2b, const float* __restrict__ b2,
    const float* __restrict__ gs, const float* __restrict__ bs,
    const short* __restrict__ Wqb,
    float* __restrict__ slots_out, float* __restrict__ qout, int emit_q) {
  __shared__ float xs[2][256], hs[2][256], sgv[2][256], ln1[2][256];
  __shared__ float giv[2][768], ghv[2][768];
  __shared__ float h1v[2][1024];
  __shared__ float pw2[4][2][256];
  __shared__ float red[2][2];
  int t = threadIdx.x;
  int w = t >> 6, lane = t & 63;
  int r0 = blockIdx.x * 2;
  #pragma unroll
  for (int row = 0; row < 2; ++row) {
    int r = r0 + row;
    float sc = 1.0f / (sums[r] + EPS);
    xs[row][t] = upd[(long)r * 256 + t] * sc;
    hs[row][t] = slots_in[(long)r * 256 + t];
  }
  __syncthreads();
  // zero own rows of upd/sums for next iteration (all reads done above)
  #pragma unroll
  for (int row = 0; row < 2; ++row) {
    upd[(long)(r0 + row) * 256 + t] = 0.f;
    if (t == row) sums[r0 + row] = 0.f;
  }
  // ---- GRU gemms: thread = 3 cols {t, t+256, t+512}
  {
    float accI[2][3] = {}, accH[2][3] = {};
    for (int k = 0; k < 256; ++k) {
      float x0 = xs[0][k], x1 = xs[1][k];
      float h0 = hs[0][k], h1 = hs[1][k];
      #pragma unroll
      for (int j = 0; j < 3; ++j) {
        float wI = wihT[k * 768 + j * 256 + t];
        float wH = whhT[k * 768 + j * 256 + t];
        accI[0][j] += x0 * wI; accI[1][j] += x1 * wI;
        accH[0][j] += h0 * wH; accH[1][j] += h1 * wH;
      }
    }
    #pragma unroll
    for (int row = 0; row < 2; ++row)
      #pragma unroll
      for (int j = 0; j < 3; ++j) {
        giv[row][j * 256 + t] = accI[row][j] + b_ih[j * 256 + t];
        ghv[row][j * 256 + t] = accH[row][j] + b_hh[j * 256 + t];
      }
  }
  __syncthreads();
  #pragma unroll
  for (int row = 0; row < 2; ++row) {
    float irv = giv[row][t], izv = giv[row][256 + t], inv = giv[row][512 + t];
    float hrv = ghv[row][t], hzv = ghv[row][256 + t], hnv = ghv[row][512 + t];
    float hv = hs[row][t];
    float rg = 1.f / (1.f + expf(-(irv + hrv)));
    float zg = 1.f / (1.f + expf(-(izv + hzv)));
    float ng = tanhf(inv + rg * hnv);
    sgv[row][t] = (1.f - zg) * ng + zg * hv;
  }
  __syncthreads();
  if (w < 2) {
    float4 sv = *(const float4*)&sgv[w][lane * 4];
    float s = sv.x + sv.y + sv.z + sv.w;
    float s2 = sv.x * sv.x + sv.y * sv.y + sv.z * sv.z + sv.w * sv.w;
    #pragma unroll
    for (int off = 32; off > 0; off >>= 1) {
      s += __shfl_xor(s, off);
      s2 += __shfl_xor(s2, off);
    }
    if (lane == 0) {
      float mu = s * (1.f / 256.f);
      red[w][0] = mu;
      red[w][1] = rsqrtf(s2 * (1.f / 256.f) - mu * mu + LN_EPS);
    }
  }
  __syncthreads();
  #pragma unroll
  for (int row = 0; row < 2; ++row)
    ln1[row][t] = (sgv[row][t] - red[row][0]) * red[row][1] * gm[t] + bm[t];
  __syncthreads();
  {
    float acc1[2][4] = {};
    for (int k = 0; k < 256; ++k) {
      ushort4 w4 = *(const ushort4*)(W1b + (long)k * 1024 + 4 * t);
      float wv[4] = {bf2f(w4.x), bf2f(w4.y), bf2f(w4.z), bf2f(w4.w)};
      float l0 = ln1[0][k], l1 = ln1[1][k];
      #pragma unroll
      for (int j = 0; j < 4; ++j) {
        acc1[0][j] += l0 * wv[j];
        acc1[1][j] += l1 * wv[j];
      }
    }
    #pragma unroll
    for (int row = 0; row < 2; ++row)
      #pragma unroll
      for (int j = 0; j < 4; ++j)
        h1v[row][4 * t + j] = fmaxf(acc1[row][j] + b1[4 * t + j], 0.f);
  }
  __syncthreads();
  {
    float acc2[2][4] = {};
    int kbase = w * 256;
    for (int kk = 0; kk < 256; ++kk) {
      int k = kbase + kk;
      ushort4 w4 = *(const ushort4*)(W2b + (long)k * 256 + 4 * lane);
      float wv[4] = {bf2f(w4.x), bf2f(w4.y), bf2f(w4.z), bf2f(w4.w)};
      float h0 = h1v[0][k], h1 = h1v[1][k];
      #pragma unroll
      for (int j = 0; j < 4; ++j) {
        acc2[0][j] += h0 * wv[j];
        acc2[1][j] += h1 * wv[j];
      }
    }
    #pragma unroll
    for (int row = 0; row < 2; ++row)
      #pragma unroll
      for (int j = 0; j < 4; ++j) pw2[w][row][4 * lane + j] = acc2[row][j];
  }
  __syncthreads();
  float outv[2];
  #pragma unroll
  for (int row = 0; row < 2; ++row) {
    float s = pw2[0][row][t] + pw2[1][row][t] + pw2[2][row][t] + pw2[3][row][t];
    outv[row] = s + b2[t] + sgv[row][t];
    slots_out[(long)(r0 + row) * 256 + t] = outv[row];
  }
  if (emit_q) {
    __syncthreads();
    xs[0][t] = outv[0];
    xs[1][t] = outv[1];
    __syncthreads();
    if (w < 2) {
      float4 sv = *(const float4*)&xs[w][lane * 4];
      float s = sv.x + sv.y + sv.z + sv.w;
      float s2 = sv.x * sv.x + sv.y * sv.y + sv.z * sv.z + sv.w * sv.w;
      #pragma unroll
      for (int off = 32; off > 0; off >>= 1) {
        s += __shfl_xor(s, off);
        s2 += __shfl_xor(s2, off);
      }
      if (lane == 0) {
        float mu = s * (1.f / 256.f);
        red[w][0] = mu;
        red[w][1] = rsqrtf(s2 * (1.f / 256.f) - mu * mu + LN_EPS);
      }
    }
    __syncthreads();
    #pragma unroll
    for (int row = 0; row < 2; ++row)
      hs[row][t] = (xs[row][t] - red[row][0]) * red[row][1] * gs[t] + bs[t];
    __syncthreads();
    float accq[2] = {};
    for (int k = 0; k < 256; ++k) {
      float wq = bf2f((u16)Wqb[k * 256 + t]);
      accq[0] += hs[0][k] * wq;
      accq[1] += hs[1][k] * wq;
    }
    #pragma unroll
    for (int row = 0; row < 2; ++row)
      qout[(long)(r0 + row) * 256 + t] = accq[row];
  }
}

// ---------------------------------------------------------------- launcher
extern "C" void kernel_launch(void* const* d_in, const int* in_sizes, int n_in,
                              void* d_out, int out_size, void* d_ws,
                              size_t ws_size, hipStream_t stream) {
  const float* features = (const float*)d_in[0];
  const float* sigma = (const float*)d_in[1];
  const float* z = (const float*)d_in[2];
  const float* slots_init_w = (const float*)d_in[3];
  const float* gf = (const float*)d_in[4];
  const float* bf = (const float*)d_in[5];
  const float* gs = (const float*)d_in[6];
  const float* bs = (const float*)d_in[7];
  const float* gm = (const float*)d_in[8];
  const float* bm = (const float*)d_in[9];
  const float* Wk = (const float*)d_in[10];
  const float* Wv = (const float*)d_in[11];
  const float* Wq = (const float*)d_in[12];
  const float* W_ih = (const float*)d_in[13];
  const float* W_hh = (const float*)d_in[14];
  const float* b_ih = (const float*)d_in[15];
  const float* b_hh = (const float*)d_in[16];
  const float* W1 = (const float*)d_in[17];
  const float* b1 = (const float*)d_in[18];
  const float* W2 = (const float*)d_in[19];
  const float* b2 = (const float*)d_in[20];

  float* ws = (float*)d_ws;
  size_t o = 0;
  short* ktv = (short*)(ws + o); o += 33554432;   // 512 x 131072 bf16
  short* Btb = (short*)(ws + o); o += 65536;      // 512 x 256 bf16
  float* wihT = ws + o; o += 196608;              // fp32 [256][768]
  float* whhT = ws + o; o += 196608;
  short* W1b = (short*)(ws + o); o += 131072;     // 256x1024 bf16
  short* W2b = (short*)(ws + o); o += 131072;     // 1024x256 bf16
  short* Wqb = (short*)(ws + o); o += 32768;      // 256x256 bf16
  float* slots = ws + o; o += 90112;
  float* qbuf = ws + o; o += 90112;
  float* upd = ws + o; o += 90112;
  float* sums = ws + o; o += 352;

  float* out_slots = (float*)d_out;
  float* out_attn = (float*)d_out + 90112;

  init_slots_kernel<<<352, 256, 0, stream>>>(slots_init_w, z, sigma, slots,
                                             upd, sums);
  wprep_kernel<<<4352, 256, 0, stream>>>(W_ih, W_hh, W1, W2, Wq, Wk, Wv,
                                         wihT, whhT, W1b, W2b, Wqb, Btb);
  gemm_kv<<<2048, 256, 0, stream>>>(features, Btb, gf, bf, ktv);
  qproj_kernel<<<352, 256, 0, stream>>>(slots, gs, bs, Wqb, qbuf);

  for (int it = 0; it < 3; ++it) {
    attn_upd<<<dim3(16, 32), 256, 0, stream>>>(
        qbuf, ktv, out_attn, sums, upd, (it == 2) ? 1 : 0);
    slot_step<<<176, 256, 0, stream>>>(
        upd, sums, slots, wihT, whhT, b_ih, b_hh, gm, bm, W1b, b1, W2b, b2,
        gs, bs, Wqb, (it == 2) ? out_slots : slots, qbuf, (it < 2) ? 1 : 0);
  }
}

// Round 8
// 689.074 us; speedup vs baseline: 1.2725x; 1.2725x over previous
//
#include <hip/hip_runtime.h>

#define EPS 1e-6f
#define LN_EPS 1e-5f

typedef unsigned short u16;
typedef unsigned int u32;
typedef short bf16x8 __attribute__((ext_vector_type(8)));
typedef float f32x4 __attribute__((ext_vector_type(4)));

__device__ __forceinline__ float bf2f(u16 u) {
  return __uint_as_float(((u32)u) << 16);
}
__device__ __forceinline__ u16 f2bf(float f) {
  u32 x = __float_as_uint(f);
  x += 0x7fffu + ((x >> 16) & 1u);
  return (u16)(x >> 16);
}

// ---------------- prep: weight prep + slots init + upd/sums zero (1 launch)
__global__ void prep_kernel(const float* __restrict__ W_ih,
                            const float* __restrict__ W_hh,
                            const float* __restrict__ W1,
                            const float* __restrict__ W2,
                            const float* __restrict__ Wq,
                            const float* __restrict__ Wk,
                            const float* __restrict__ Wv,
                            const float* __restrict__ slots_init_w,
                            const float* __restrict__ z,
                            const float* __restrict__ sigma,
                            float* __restrict__ wihT, float* __restrict__ whhT,
                            short* __restrict__ W1b, short* __restrict__ W2b,
                            short* __restrict__ Wqb, short* __restrict__ Btb,
                            float* __restrict__ slots, float* __restrict__ upd,
                            float* __restrict__ sums) {
  int e = blockIdx.x * 256 + threadIdx.x;
  if (e < 196608) {
    int j = e >> 8, d = e & 255;
    wihT[d * 768 + j] = W_ih[e];
  } else if (e < 393216) {
    int e2 = e - 196608;
    int j = e2 >> 8, d = e2 & 255;
    whhT[d * 768 + j] = W_hh[e2];
  } else if (e < 655360) {
    int e2 = e - 393216;
    W1b[e2] = (short)f2bf(W1[e2]);
  } else if (e < 917504) {
    int e2 = e - 655360;
    W2b[e2] = (short)f2bf(W2[e2]);
  } else if (e < 983040) {
    int e2 = e - 917504;
    Wqb[e2] = (short)f2bf(Wq[e2]);
  } else if (e < 1114112) {
    int e2 = e - 983040;
    int f = e2 >> 9, j = e2 & 511;
    float v = (j < 256) ? Wk[f * 256 + j] : Wv[f * 256 + (j - 256)];
    Btb[j * 256 + f] = (short)f2bf(v);
  } else if (e < 1204224) {
    int i = e - 1114112;  // < 90112
    int s = i & 255;
    int k = (i >> 8) % 11;
    float wv = slots_init_w[k * 256 + s];
    slots[i] = wv + z[i] * sigma[0] * wv;
    upd[i] = 0.f;
    if (i < 352) sums[i] = 0.f;
  }
}

// --------------------------------------------------- MFMA k+v projection
// [k|v] = LN(features) @ [Wk|Wv]. 64-row blocks (grid 2048); full-K A tile
// (fused LN -> bf16) staged once; 16 (jq,ks) steps, double-buffered 16KB B
// tiles via global_load_lds (round-5 proven structure).
// jq<2 (k half): SWAPPED mfma -> D[f][i'] col=i, row=f -> knorm[i][f] packed
// in f. jq>=2 (v half): NORMAL mfma -> D[s][i] col=s... col=j=s, row=i ->
// vT[s][i] packed in i.
// A swizzle: chunk q of row r at p = (q & 24) | ((q + 2*(q>>3) + r) & 7).
__global__ __launch_bounds__(256) void gemm_kv(
    const float* __restrict__ feat, const short* __restrict__ Btb,
    const float* __restrict__ gf, const float* __restrict__ bfp,
    short* __restrict__ knorm, short* __restrict__ vT) {
  __shared__ short As[16384];    // 64 rows x 256 k
  __shared__ short Bs[2][8192];  // 2 x (128 j x 64 k)
  int t = threadIdx.x;
  int w = t >> 6, lane = t & 63;
  int quad = lane >> 4, l16 = lane & 15;
  int i0 = blockIdx.x * 64;
  int wi = (w & 1) * 32, wj = (w >> 1) * 64;

  // ---- prefetch B(step 0) into buf 0
  {
    #pragma unroll
    for (int c = 0; c < 4; ++c) {
      int lin = c * 256 + t;
      int jr = lin >> 3, p = lin & 7;
      int q = (p - jr) & 7;
      const short* gB = Btb + (long)jr * 256 + q * 8;
      __builtin_amdgcn_global_load_lds(
          (const __attribute__((address_space(1))) void*)gB,
          (__attribute__((address_space(3))) void*)&Bs[0][lin * 8], 16, 0, 0);
    }
  }

  // ---- stage A: fused LN stats + bf16 cvt (thread = quarter of row)
  {
    int r = t >> 2;
    int qd = t & 3;
    const float* frow = feat + (long)(i0 + r) * 256 + qd * 64;
    float4 fv[16];
    float s = 0.f, s2 = 0.f;
    #pragma unroll
    for (int i = 0; i < 16; ++i) {
      fv[i] = *(const float4*)(frow + i * 4);
      s += fv[i].x + fv[i].y + fv[i].z + fv[i].w;
      s2 += fv[i].x * fv[i].x + fv[i].y * fv[i].y + fv[i].z * fv[i].z +
            fv[i].w * fv[i].w;
    }
    s += __shfl_xor(s, 1); s2 += __shfl_xor(s2, 1);
    s += __shfl_xor(s, 2); s2 += __shfl_xor(s2, 2);
    float mu = s * (1.f / 256.f);
    float rs = rsqrtf(s2 * (1.f / 256.f) - mu * mu + LN_EPS);
    #pragma unroll
    for (int c = 0; c < 8; ++c) {
      float4 a = fv[c * 2], b = fv[c * 2 + 1];
      int fb = qd * 64 + c * 8;
      float4 g0 = *(const float4*)(gf + fb);
      float4 g1 = *(const float4*)(gf + fb + 4);
      float4 e0 = *(const float4*)(bfp + fb);
      float4 e1 = *(const float4*)(bfp + fb + 4);
      bf16x8 pk;
      pk[0] = (short)f2bf((a.x - mu) * rs * g0.x + e0.x);
      pk[1] = (short)f2bf((a.y - mu) * rs * g0.y + e0.y);
      pk[2] = (short)f2bf((a.z - mu) * rs * g0.z + e0.z);
      pk[3] = (short)f2bf((a.w - mu) * rs * g0.w + e0.w);
      pk[4] = (short)f2bf((b.x - mu) * rs * g1.x + e1.x);
      pk[5] = (short)f2bf((b.y - mu) * rs * g1.y + e1.y);
      pk[6] = (short)f2bf((b.z - mu) * rs * g1.z + e1.z);
      pk[7] = (short)f2bf((b.w - mu) * rs * g1.w + e1.w);
      int p = qd * 8 + ((c + 2 * qd + r) & 7);
      *(bf16x8*)&As[r * 256 + p * 8] = pk;
    }
  }
  __syncthreads();

  f32x4 acc[2][4];
  #pragma unroll
  for (int a = 0; a < 2; ++a)
    #pragma unroll
    for (int b = 0; b < 4; ++b) acc[a][b] = (f32x4){0.f, 0.f, 0.f, 0.f};

  for (int idx = 0; idx < 16; ++idx) {
    int jq = idx >> 2, ks = idx & 3;
    int buf = idx & 1;
    if (idx < 15) {
      int jn = (idx + 1) >> 2, kn = (idx + 1) & 3;
      #pragma unroll
      for (int c = 0; c < 4; ++c) {
        int lin = c * 256 + t;
        int jr = lin >> 3, p = lin & 7;
        int q = (p - jr) & 7;
        const short* gB = Btb + (long)(jn * 128 + jr) * 256 + kn * 64 + q * 8;
        __builtin_amdgcn_global_load_lds(
            (const __attribute__((address_space(1))) void*)gB,
            (__attribute__((address_space(3))) void*)&Bs[buf ^ 1][lin * 8],
            16, 0, 0);
      }
    }
    #pragma unroll
    for (int kh = 0; kh < 2; ++kh) {
      bf16x8 af[2], bfr[4];
      #pragma unroll
      for (int mi = 0; mi < 2; ++mi) {
        int m = wi + mi * 16 + l16;
        int p = ks * 8 + ((kh * 4 + quad + 2 * ks + m) & 7);
        af[mi] = *(const bf16x8*)&As[m * 256 + p * 8];
      }
      #pragma unroll
      for (int ni = 0; ni < 4; ++ni) {
        int j = wj + ni * 16 + l16;
        int p = ((kh * 4 + quad) + j) & 7;
        bfr[ni] = *(const bf16x8*)&Bs[buf][j * 64 + p * 8];
      }
      if (jq < 2) {
        // k half: swapped operands -> D rows = B(j=f) rows, cols = A(i) rows
        #pragma unroll
        for (int mi = 0; mi < 2; ++mi)
          #pragma unroll
          for (int ni = 0; ni < 4; ++ni)
            acc[mi][ni] = __builtin_amdgcn_mfma_f32_16x16x32_bf16(
                bfr[ni], af[mi], acc[mi][ni], 0, 0, 0);
      } else {
        // v half: normal -> D rows = A(i) rows, cols = B(j=s) rows
        #pragma unroll
        for (int mi = 0; mi < 2; ++mi)
          #pragma unroll
          for (int ni = 0; ni < 4; ++ni)
            acc[mi][ni] = __builtin_amdgcn_mfma_f32_16x16x32_bf16(
                af[mi], bfr[ni], acc[mi][ni], 0, 0, 0);
      }
    }
    if (ks == 3) {
      if (jq < 2) {
        // col(l16)=i, row(quad*4+reg)=f -> knorm[i][f] packed in f
        #pragma unroll
        for (int mi = 0; mi < 2; ++mi) {
          long i = i0 + wi + mi * 16 + l16;
          #pragma unroll
          for (int ni = 0; ni < 4; ++ni) {
            int fb = jq * 128 + wj + ni * 16 + quad * 4;
            ushort4 u;
            u.x = f2bf(acc[mi][ni][0]);
            u.y = f2bf(acc[mi][ni][1]);
            u.z = f2bf(acc[mi][ni][2]);
            u.w = f2bf(acc[mi][ni][3]);
            *(ushort4*)&knorm[i * 256 + fb] = u;
          }
        }
      } else {
        // col(l16)=s, row(quad*4+reg)=i -> vT[s][i] packed in i
        #pragma unroll
        for (int ni = 0; ni < 4; ++ni) {
          int s = (jq - 2) * 128 + wj + ni * 16 + l16;
          #pragma unroll
          for (int mi = 0; mi < 2; ++mi) {
            long ib = i0 + wi + mi * 16 + quad * 4;
            ushort4 u;
            u.x = f2bf(acc[mi][ni][0]);
            u.y = f2bf(acc[mi][ni][1]);
            u.z = f2bf(acc[mi][ni][2]);
            u.w = f2bf(acc[mi][ni][3]);
            *(ushort4*)&vT[(long)s * 131072 + ib] = u;
          }
        }
      }
      #pragma unroll
      for (int a = 0; a < 2; ++a)
        #pragma unroll
        for (int b = 0; b < 4; ++b) acc[a][b] = (f32x4){0.f, 0.f, 0.f, 0.f};
    }
    __syncthreads();
  }
}

// ----------------------------------------------------- q projection (iter 0)
__global__ __launch_bounds__(256) void qproj_kernel(
    const float* __restrict__ slots, const float* __restrict__ gs,
    const float* __restrict__ bs, const short* __restrict__ Wqb,
    float* __restrict__ qout) {
  __shared__ float lnq[256];
  __shared__ float red[8];
  int row = blockIdx.x, t = threadIdx.x;
  int w = t >> 6, lane = t & 63;
  float x = slots[(long)row * 256 + t];
  float s = x, s2 = x * x;
  #pragma unroll
  for (int off = 32; off > 0; off >>= 1) {
    s += __shfl_xor(s, off);
    s2 += __shfl_xor(s2, off);
  }
  if (lane == 0) { red[w * 2] = s; red[w * 2 + 1] = s2; }
  __syncthreads();
  float st = red[0] + red[2] + red[4] + red[6];
  float st2 = red[1] + red[3] + red[5] + red[7];
  float mu = st * (1.f / 256.f);
  float rs = rsqrtf(st2 * (1.f / 256.f) - mu * mu + LN_EPS);
  lnq[t] = (x - mu) * rs * gs[t] + bs[t];
  __syncthreads();
  float acc = 0.f;
  for (int k = 0; k < 256; ++k)
    acc += lnq[k] * bf2f((u16)Wqb[k * 256 + t]);
  qout[(long)row * 256 + t] = acc;
}

// --------------------------- fused MFMA attention softmax + updates
// Grid (8,32): block = 512 n of batch b, 4 waves (wave w -> n w*128..+127).
// Phase 1 (QK^T via MFMA): A = knorm rows n, B = q bf16 in LDS rows kk
// (rows 11..15 zero). D[n][kk]: lane l16 = kk, reg rows = n. Softmax over kk
// = masked butterfly over l16 (xor 1,2,4,8). P -> LDS bf16 [kk][n] (B-op
// layout for phase 2) + per-wave sums atomics + attn out on last iter.
// Phase 2 (P.V^T via MFMA): upd^T[s][kk] = sum_n vT[s][n] P[kk][n];
// lanes l16<11 atomicAdd (UNNORMALIZED; slot_step divides by sums+EPS).
__global__ __launch_bounds__(256) void attn_upd(
    const float* __restrict__ q, const short* __restrict__ knorm,
    const short* __restrict__ vT, float* __restrict__ attn_out,
    float* __restrict__ sums, float* __restrict__ upd, int emit_attn) {
  __shared__ short qs[16 * 264];  // [kk][f] bf16, stride 264
  __shared__ short ps[16 * 520];  // [kk][n] bf16, stride 520
  int b = blockIdx.y;
  int n0 = blockIdx.x * 512;
  int t = threadIdx.x, lane = t & 63;
  int w = t >> 6, quad = lane >> 4, l16 = lane & 15;
  // stage q (rows 11..15 zero)
  for (int e = t; e < 5 * 264; e += 256) qs[11 * 264 + e] = 0;
  for (int e = t; e < 2816; e += 256) {
    int kk = e >> 8, f = e & 255;
    qs[kk * 264 + f] = (short)f2bf(q[b * 2816 + e]);
  }
  __syncthreads();
  // ---- phase 1: 8 n-tiles x 8 f-chunks of MFMA
  f32x4 acc[8];
  #pragma unroll
  for (int mi = 0; mi < 8; ++mi) acc[mi] = (f32x4){0.f, 0.f, 0.f, 0.f};
  long nbase = (long)b * 4096 + n0 + w * 128;
  const short* kb = knorm + (nbase + l16) * 256 + quad * 8;
  #pragma unroll
  for (int c = 0; c < 8; ++c) {
    bf16x8 qf = *(const bf16x8*)&qs[l16 * 264 + c * 32 + quad * 8];
    #pragma unroll
    for (int mi = 0; mi < 8; ++mi) {
      bf16x8 kf = *(const bf16x8*)&kb[mi * 16 * 256 + c * 32];
      acc[mi] = __builtin_amdgcn_mfma_f32_16x16x32_bf16(kf, qf, acc[mi], 0, 0, 0);
    }
  }
  bool valid = l16 < 11;
  float slsum = 0.f;
  #pragma unroll
  for (int mi = 0; mi < 8; ++mi) {
    float4 pv;
    #pragma unroll
    for (int r = 0; r < 4; ++r) {
      float L = acc[mi][r] * 0.0625f;  // 256^-0.5
      float Lm = valid ? L : -1e30f;
      Lm = fmaxf(Lm, __shfl_xor(Lm, 1));
      Lm = fmaxf(Lm, __shfl_xor(Lm, 2));
      Lm = fmaxf(Lm, __shfl_xor(Lm, 4));
      Lm = fmaxf(Lm, __shfl_xor(Lm, 8));
      float p = valid ? expf(L - Lm) : 0.f;
      float ss = p;
      ss += __shfl_xor(ss, 1);
      ss += __shfl_xor(ss, 2);
      ss += __shfl_xor(ss, 4);
      ss += __shfl_xor(ss, 8);
      p = p / ss;
      (&pv.x)[r] = p;
      slsum += p;
      ps[l16 * 520 + w * 128 + mi * 16 + quad * 4 + r] = (short)f2bf(p);
    }
    if (emit_attn && valid)
      *(float4*)(attn_out + ((long)b * 11 + l16) * 4096 + n0 + w * 128 +
                 mi * 16 + quad * 4) = pv;
  }
  slsum += __shfl_xor(slsum, 16);
  slsum += __shfl_xor(slsum, 32);
  if (valid && quad == 0) atomicAdd(&sums[b * 11 + l16], slsum);
  __syncthreads();
  // ---- phase 2: wave w -> s-tiles w*4..w*4+3
  f32x4 acc4[4];
  #pragma unroll
  for (int mi = 0; mi < 4; ++mi) acc4[mi] = (f32x4){0.f, 0.f, 0.f, 0.f};
  #pragma unroll
  for (int kst = 0; kst < 16; ++kst) {
    int nb = kst * 32 + quad * 8;
    bf16x8 bps = *(const bf16x8*)&ps[l16 * 520 + nb];
    #pragma unroll
    for (int mi = 0; mi < 4; ++mi) {
      int s = (w * 4 + mi) * 16 + l16;
      bf16x8 av =
          *(const bf16x8*)&vT[(long)s * 131072 + (long)b * 4096 + n0 + nb];
      acc4[mi] =
          __builtin_amdgcn_mfma_f32_16x16x32_bf16(av, bps, acc4[mi], 0, 0, 0);
    }
  }
  if (l16 < 11) {
    #pragma unroll
    for (int mi = 0; mi < 4; ++mi) {
      int sb = (w * 4 + mi) * 16 + quad * 4;
      #pragma unroll
      for (int r = 0; r < 4; ++r)
        atomicAdd(&upd[((long)b * 11 + l16) * 256 + sb + r], acc4[mi][r]);
    }
  }
}

// -------------------------------------------- fused slot step (2 rows/block)
__global__ __launch_bounds__(256) void slot_step(
    float* __restrict__ upd, float* __restrict__ sums,
    const float* __restrict__ slots_in,
    const float* __restrict__ wihT, const float* __restrict__ whhT,
    const float* __restrict__ b_ih, const float* __restrict__ b_hh,
    const float* __restrict__ gm, const float* __restrict__ bm,
    const short* __restrict__ W1b, const float* __restrict__ b1,
    const short* __restrict__ W2b, const float* __restrict__ b2,
    const float* __restrict__ gs, const float* __restrict__ bs,
    const short* __restrict__ Wqb,
    float* __restrict__ slots_out, float* __restrict__ qout, int emit_q) {
  __shared__ float xs[2][256], hs[2][256], sgv[2][256], ln1[2][256];
  __shared__ float giv[2][768], ghv[2][768];
  __shared__ float h1v[2][1024];
  __shared__ float pw2[4][2][256];
  __shared__ float red[2][2];
  int t = threadIdx.x;
  int w = t >> 6, lane = t & 63;
  int r0 = blockIdx.x * 2;
  #pragma unroll
  for (int row = 0; row < 2; ++row) {
    int r = r0 + row;
    float sc = 1.0f / (sums[r] + EPS);
    xs[row][t] = upd[(long)r * 256 + t] * sc;
    hs[row][t] = slots_in[(long)r * 256 + t];
  }
  __syncthreads();
  #pragma unroll
  for (int row = 0; row < 2; ++row) {
    upd[(long)(r0 + row) * 256 + t] = 0.f;
    if (t == row) sums[r0 + row] = 0.f;
  }
  {
    float accI[2][3] = {}, accH[2][3] = {};
    for (int k = 0; k < 256; ++k) {
      float x0 = xs[0][k], x1 = xs[1][k];
      float h0 = hs[0][k], h1 = hs[1][k];
      #pragma unroll
      for (int j = 0; j < 3; ++j) {
        float wI = wihT[k * 768 + j * 256 + t];
        float wH = whhT[k * 768 + j * 256 + t];
        accI[0][j] += x0 * wI; accI[1][j] += x1 * wI;
        accH[0][j] += h0 * wH; accH[1][j] += h1 * wH;
      }
    }
    #pragma unroll
    for (int row = 0; row < 2; ++row)
      #pragma unroll
      for (int j = 0; j < 3; ++j) {
        giv[row][j * 256 + t] = accI[row][j] + b_ih[j * 256 + t];
        ghv[row][j * 256 + t] = accH[row][j] + b_hh[j * 256 + t];
      }
  }
  __syncthreads();
  #pragma unroll
  for (int row = 0; row < 2; ++row) {
    float irv = giv[row][t], izv = giv[row][256 + t], inv = giv[row][512 + t];
    float hrv = ghv[row][t], hzv = ghv[row][256 + t], hnv = ghv[row][512 + t];
    float hv = hs[row][t];
    float rg = 1.f / (1.f + expf(-(irv + hrv)));
    float zg = 1.f / (1.f + expf(-(izv + hzv)));
    float ng = tanhf(inv + rg * hnv);
    sgv[row][t] = (1.f - zg) * ng + zg * hv;
  }
  __syncthreads();
  if (w < 2) {
    float4 sv = *(const float4*)&sgv[w][lane * 4];
    float s = sv.x + sv.y + sv.z + sv.w;
    float s2 = sv.x * sv.x + sv.y * sv.y + sv.z * sv.z + sv.w * sv.w;
    #pragma unroll
    for (int off = 32; off > 0; off >>= 1) {
      s += __shfl_xor(s, off);
      s2 += __shfl_xor(s2, off);
    }
    if (lane == 0) {
      float mu = s * (1.f / 256.f);
      red[w][0] = mu;
      red[w][1] = rsqrtf(s2 * (1.f / 256.f) - mu * mu + LN_EPS);
    }
  }
  __syncthreads();
  #pragma unroll
  for (int row = 0; row < 2; ++row)
    ln1[row][t] = (sgv[row][t] - red[row][0]) * red[row][1] * gm[t] + bm[t];
  __syncthreads();
  {
    float acc1[2][4] = {};
    for (int k = 0; k < 256; ++k) {
      ushort4 w4 = *(const ushort4*)(W1b + (long)k * 1024 + 4 * t);
      float wv[4] = {bf2f(w4.x), bf2f(w4.y), bf2f(w4.z), bf2f(w4.w)};
      float l0 = ln1[0][k], l1 = ln1[1][k];
      #pragma unroll
      for (int j = 0; j < 4; ++j) {
        acc1[0][j] += l0 * wv[j];
        acc1[1][j] += l1 * wv[j];
      }
    }
    #pragma unroll
    for (int row = 0; row < 2; ++row)
      #pragma unroll
      for (int j = 0; j < 4; ++j)
        h1v[row][4 * t + j] = fmaxf(acc1[row][j] + b1[4 * t + j], 0.f);
  }
  __syncthreads();
  {
    float acc2[2][4] = {};
    int kbase = w * 256;
    for (int kk = 0; kk < 256; ++kk) {
      int k = kbase + kk;
      ushort4 w4 = *(const ushort4*)(W2b + (long)k * 256 + 4 * lane);
      float wv[4] = {bf2f(w4.x), bf2f(w4.y), bf2f(w4.z), bf2f(w4.w)};
      float h0 = h1v[0][k], h1 = h1v[1][k];
      #pragma unroll
      for (int j = 0; j < 4; ++j) {
        acc2[0][j] += h0 * wv[j];
        acc2[1][j] += h1 * wv[j];
      }
    }
    #pragma unroll
    for (int row = 0; row < 2; ++row)
      #pragma unroll
      for (int j = 0; j < 4; ++j) pw2[w][row][4 * lane + j] = acc2[row][j];
  }
  __syncthreads();
  float outv[2];
  #pragma unroll
  for (int row = 0; row < 2; ++row) {
    float s = pw2[0][row][t] + pw2[1][row][t] + pw2[2][row][t] + pw2[3][row][t];
    outv[row] = s + b2[t] + sgv[row][t];
    slots_out[(long)(r0 + row) * 256 + t] = outv[row];
  }
  if (emit_q) {
    __syncthreads();
    xs[0][t] = outv[0];
    xs[1][t] = outv[1];
    __syncthreads();
    if (w < 2) {
      float4 sv = *(const float4*)&xs[w][lane * 4];
      float s = sv.x + sv.y + sv.z + sv.w;
      float s2 = sv.x * sv.x + sv.y * sv.y + sv.z * sv.z + sv.w * sv.w;
      #pragma unroll
      for (int off = 32; off > 0; off >>= 1) {
        s += __shfl_xor(s, off);
        s2 += __shfl_xor(s2, off);
      }
      if (lane == 0) {
        float mu = s * (1.f / 256.f);
        red[w][0] = mu;
        red[w][1] = rsqrtf(s2 * (1.f / 256.f) - mu * mu + LN_EPS);
      }
    }
    __syncthreads();
    #pragma unroll
    for (int row = 0; row < 2; ++row)
      hs[row][t] = (xs[row][t] - red[row][0]) * red[row][1] * gs[t] + bs[t];
    __syncthreads();
    float accq[2] = {};
    for (int k = 0; k < 256; ++k) {
      float wq = bf2f((u16)Wqb[k * 256 + t]);
      accq[0] += hs[0][k] * wq;
      accq[1] += hs[1][k] * wq;
    }
    #pragma unroll
    for (int row = 0; row < 2; ++row)
      qout[(long)(r0 + row) * 256 + t] = accq[row];
  }
}

// ---------------------------------------------------------------- launcher
extern "C" void kernel_launch(void* const* d_in, const int* in_sizes, int n_in,
                              void* d_out, int out_size, void* d_ws,
                              size_t ws_size, hipStream_t stream) {
  const float* features = (const float*)d_in[0];
  const float* sigma = (const float*)d_in[1];
  const float* z = (const float*)d_in[2];
  const float* slots_init_w = (const float*)d_in[3];
  const float* gf = (const float*)d_in[4];
  const float* bf = (const float*)d_in[5];
  const float* gs = (const float*)d_in[6];
  const float* bs = (const float*)d_in[7];
  const float* gm = (const float*)d_in[8];
  const float* bm = (const float*)d_in[9];
  const float* Wk = (const float*)d_in[10];
  const float* Wv = (const float*)d_in[11];
  const float* Wq = (const float*)d_in[12];
  const float* W_ih = (const float*)d_in[13];
  const float* W_hh = (const float*)d_in[14];
  const float* b_ih = (const float*)d_in[15];
  const float* b_hh = (const float*)d_in[16];
  const float* W1 = (const float*)d_in[17];
  const float* b1 = (const float*)d_in[18];
  const float* W2 = (const float*)d_in[19];
  const float* b2 = (const float*)d_in[20];

  float* ws = (float*)d_ws;
  size_t o = 0;
  short* knorm = (short*)(ws + o); o += 16777216;  // 131072x256 bf16 (64MB)
  short* vT = (short*)(ws + o); o += 16777216;     // 256x131072 bf16 (64MB)
  short* Btb = (short*)(ws + o); o += 65536;       // 512x256 bf16
  float* wihT = ws + o; o += 196608;               // fp32 [256][768]
  float* whhT = ws + o; o += 196608;
  short* W1b = (short*)(ws + o); o += 131072;      // 256x1024 bf16
  short* W2b = (short*)(ws + o); o += 131072;      // 1024x256 bf16
  short* Wqb = (short*)(ws + o); o += 32768;       // 256x256 bf16
  float* slots = ws + o; o += 90112;
  float* qbuf = ws + o; o += 90112;
  float* upd = ws + o; o += 90112;
  float* sums = ws + o; o += 352;

  float* out_slots = (float*)d_out;
  float* out_attn = (float*)d_out + 90112;

  prep_kernel<<<4704, 256, 0, stream>>>(W_ih, W_hh, W1, W2, Wq, Wk, Wv,
                                        slots_init_w, z, sigma, wihT, whhT,
                                        W1b, W2b, Wqb, Btb, slots, upd, sums);
  gemm_kv<<<2048, 256, 0, stream>>>(features, Btb, gf, bf, knorm, vT);
  qproj_kernel<<<352, 256, 0, stream>>>(slots, gs, bs, Wqb, qbuf);

  for (int it = 0; it < 3; ++it) {
    attn_upd<<<dim3(8, 32), 256, 0, stream>>>(
        qbuf, knorm, vT, out_attn, sums, upd, (it == 2) ? 1 : 0);
    slot_step<<<176, 256, 0, stream>>>(
        upd, sums, slots, wihT, whhT, b_ih, b_hh, gm, bm, W1b, b1, W2b, b2,
        gs, bs, Wqb, (it == 2) ? out_slots : slots, qbuf, (it < 2) ? 1 : 0);
  }
}